// Round 11
// baseline (27990.659 us; speedup 1.0000x reference)
//
#include <hip/hip_runtime.h>
#include <hip/hip_cooperative_groups.h>
#include <stdint.h>

namespace cg = cooperative_groups;

// ----------------------------------------------------------------------------
// 2-layer LSTM (T=8192, IN=9, H=1024) + Linear(H->1), fp32, one cooperative
// kernel, 256 blocks x 512 threads (1 block/CU).
//
// Model (r2/r6/r7 counters): weights stay on-CU (VGPR/AGPR). WRITE_SIZE =
// exactly 512MB = publish-sector floor (invariant). Round time 2.37us is
// LLC *request serialization*: 256 blocks x 1024 x 16B coherent polls/round
// = 2048 requests per hot line per round. r7 (more in-flight) made it WORSE.
//
// THIS ROUND: per-XCD relay. Each block hubs 1/32 of the mailboxes
// (LLC sc0 sc1 -> per-XCD mirror store), siblings poll the mirror with
// sc0-only loads served by the XCD's shared L2. LLC poll requests/round drop
// 262144 -> ~8192 (32x). XCD id via s_getreg(HW_REG_XCC_ID) [m09-verified];
// rank via startup atomicAdd + one grid.sync() (placement-agnostic).
// SAFETY: bounded mirror polls (2000 retries) + sticky per-block fallback to
// direct LLC polling -> a wrong L2-visibility assumption degrades to r6 perf,
// never deadlocks.
//
// Mailboxes pub[slot][unit] = u64{seq(hi)|fp32 h(lo)}, relaxed agent stores;
// ring depth 4; every block gates each round on the COMPLETE previous round
// => inter-block skew <= 1 round => distance-4 slot reuse race-free (mirror
// slots: same argument within an XCD). 0xAA ws poison = "empty" marker.
// ----------------------------------------------------------------------------

#define TSTEPS 8192
#define HDIM   1024
#define BS     512
#define NBLK   256
#define RINGM  3        // ring mask (depth 4)

typedef unsigned long long u64;
typedef unsigned int u32;
typedef __attribute__((ext_vector_type(4))) unsigned int u32x4;

__device__ __forceinline__ float sigm(float x)  { return 1.0f / (1.0f + __expf(-x)); }
__device__ __forceinline__ float tanh_(float x) { return 1.0f - 2.0f / (__expf(2.0f * x) + 1.0f); }
__device__ __forceinline__ float dot4(float4 a, float4 b) {
  return a.x * b.x + a.y * b.y + a.z * b.z + a.w * b.w;
}
__device__ __forceinline__ void pin4(float4& v) {
  asm volatile("" : "+v"(v.x), "+v"(v.y), "+v"(v.z), "+v"(v.w));
}

// 16B LLC-coherent load (bypass L1+L2): for hub polls of the global mailbox.
__device__ __forceinline__ void ld16cc(u32x4& r, const u64* p) {
  asm volatile("global_load_dwordx4 %0, %1, off sc0 sc1" : "=&v"(r) : "v"(p));
}
// 16B L2-scope load (bypass L1 only): for mirror polls within an XCD.
__device__ __forceinline__ void ld16l2(u32x4& r, const u64* p) {
  asm volatile("global_load_dwordx4 %0, %1, off sc0" : "=&v"(r) : "v"(p));
}
// Plain 16B store: lands in the XCD's shared L2 (L1 is write-through).
__device__ __forceinline__ void st16(u64* p, u32x4 v) {
  asm volatile("global_store_dwordx4 %0, %1, off" :: "v"(p), "v"(v) : "memory");
}
__device__ __forceinline__ void wait1(u32x4& a) {
  asm volatile("s_waitcnt vmcnt(0)" : "+v"(a) :: "memory");
}
__device__ __forceinline__ void wait2(u32x4& a, u32x4& b) {
  asm volatile("s_waitcnt vmcnt(0)" : "+v"(a), "+v"(b) :: "memory");
}

// 8B atomic poll (fallback + epilogue): always correct, LLC-coherent.
__device__ __forceinline__ u64 pollslot(const u64* p, u32 want) {
  u64 v = __hip_atomic_load(p, __ATOMIC_RELAXED, __HIP_MEMORY_SCOPE_AGENT);
  while ((u32)(v >> 32) != want) {
    __builtin_amdgcn_s_sleep(2);
    v = __hip_atomic_load(p, __ATOMIC_RELAXED, __HIP_MEMORY_SCOPE_AGENT);
  }
  return v;
}

__device__ __forceinline__ void publish(u64* p, u32 seq, float h) {
  u64 v = ((u64)seq << 32) | (u64)__float_as_uint(h);
  __hip_atomic_store(p, v, __ATOMIC_RELAXED, __HIP_MEMORY_SCOPE_AGENT);
}

__global__ void
__launch_bounds__(BS)
__attribute__((amdgpu_waves_per_eu(2, 2)))
lstm_fused(
    const float* __restrict__ xin,   // [T][9]
    const float* __restrict__ wih0,  // [4H][9]
    const float* __restrict__ whh0,  // [4H][H]
    const float* __restrict__ bih0, const float* __restrict__ bhh0,
    const float* __restrict__ wih1,  // [4H][H]
    const float* __restrict__ whh1,  // [4H][H]
    const float* __restrict__ bih1, const float* __restrict__ bhh1,
    const float* __restrict__ wlin, const float* __restrict__ blin,
    float* __restrict__ out,
    u64* __restrict__ pub1, u64* __restrict__ pub2,  // [4][HDIM] each
    u64* __restrict__ mir,                           // [8][4][2048]
    u32* __restrict__ cnt)                           // [8]
{
  const int b   = blockIdx.x;
  const int tid = threadIdx.x;
  const int wv  = tid >> 6;
  const int ln  = tid & 63;
  const bool isL0 = (wv < 4);
  const int unit = 4 * b + (wv & 3);       // hidden unit this wave owns

  __shared__ __align__(16) float hA[2][HDIM]; // h1, double-buffered by r&1
  __shared__ __align__(16) float hB[2][HDIM]; // h2, double-buffered by r&1
  __shared__ float red8[8];
  __shared__ u32 sh_xr[2];                    // {xcd, rank}
  __shared__ int useDir;                      // sticky fallback flag

  if (tid == 0) {
    u32 x;
    asm volatile("s_getreg_b32 %0, hwreg(HW_REG_XCC_ID)" : "=s"(x));
    x &= 7;
    sh_xr[0] = x;
    sh_xr[1] = atomicAdd(&cnt[x], 1u);
    useDir = 0;
  }
  __syncthreads();
  const u32 xcd = sh_xr[0];
  const u32 rank = sh_xr[1];

  // ---- weights -> registers (pinned; overflow lives in AGPRs) ------------
  float4 wrr[4][4];                         // L0: w_hh0 rows | L1: w_hh1 rows
  {
    const float* WR = isL0 ? whh0 : whh1;
    #pragma unroll
    for (int g = 0; g < 4; ++g)
      #pragma unroll
      for (int j = 0; j < 4; ++j) {
        wrr[g][j] = *reinterpret_cast<const float4*>(
            WR + (size_t)(g * HDIM + unit) * HDIM + 4 * ln + 256 * j);
        pin4(wrr[g][j]);
      }
  }
  float4 wii[4][4];                         // L1 only: w_ih1 rows
  if (!isL0) {
    #pragma unroll
    for (int g = 0; g < 4; ++g)
      #pragma unroll
      for (int j = 0; j < 4; ++j) {
        wii[g][j] = *reinterpret_cast<const float4*>(
            wih1 + (size_t)(g * HDIM + unit) * HDIM + 4 * ln + 256 * j);
        pin4(wii[g][j]);
      }
  }
  float wxr[4][9];                          // L0 only: w_ih0 rows
  if (isL0) {
    #pragma unroll
    for (int g = 0; g < 4; ++g) {
      #pragma unroll
      for (int k = 0; k < 9; ++k)
        wxr[g][k] = wih0[(size_t)(g * HDIM + unit) * 9 + k];
      asm volatile("" : "+v"(wxr[g][0]), "+v"(wxr[g][1]), "+v"(wxr[g][2]),
                        "+v"(wxr[g][3]), "+v"(wxr[g][4]), "+v"(wxr[g][5]),
                        "+v"(wxr[g][6]), "+v"(wxr[g][7]), "+v"(wxr[g][8]));
    }
  }
  float bias[4];
  #pragma unroll
  for (int g = 0; g < 4; ++g)
    bias[g] = isL0 ? (bih0[g * HDIM + unit] + bhh0[g * HDIM + unit])
                   : (bih1[g * HDIM + unit] + bhh1[g * HDIM + unit]);
  asm volatile("" : "+v"(bias[0]), "+v"(bias[1]), "+v"(bias[2]), "+v"(bias[3]));

  // All ranks registered before anyone reads its XCD population.
  cg::this_grid().sync();
  const u32 nloc = __hip_atomic_load(&cnt[xcd], __ATOMIC_RELAXED,
                                     __HIP_MEMORY_SCOPE_AGENT);
  u64* mirx = mir + (size_t)xcd * (4 * 2048);

  float c = 0.0f;                           // cell state (replicated per lane)

  // ======================== round loop ====================================
  for (int r = 0; r <= TSTEPS; ++r) {
    float xr[9];
    if (isL0 && r < TSTEPS) {
      #pragma unroll
      for (int k = 0; k < 9; ++k) xr[k] = xin[r * 9 + k];
    }

    const int i2 = tid * 2;
    float* hAr = hA[r & 1];
    float* hBr = hB[r & 1];

    if (r == 0) {
      hA[0][i2] = 0.0f; hA[0][i2 + 1] = 0.0f;
      hB[0][i2] = 0.0f; hB[0][i2 + 1] = 0.0f;
      hB[1][i2] = 0.0f; hB[1][i2 + 1] = 0.0f;  // read at r==1 (h2(-1)=0)
    } else {
      const u32 wA = (u32)r, wB = (u32)(r - 1);

      // ---- hub: wave 0, lanes 0..31 forward segments pub -> mirror ------
      if (wv == 0 && ln < 32) {
        for (u32 s = rank; s < 32; s += nloc) {
          if (r == 1 && s >= 16) break;      // h2 stream not yet published
          const u64* src; u32 want;
          if (s < 16) {
            src = pub1 + (size_t)((r - 1) & RINGM) * HDIM + s * 64 + 2 * ln;
            want = wA;
          } else {
            src = pub2 + (size_t)((r - 2) & RINGM) * HDIM + (s - 16) * 64 + 2 * ln;
            want = wB;
          }
          u32x4 v = {0, 0, 0, 0};
          ld16cc(v, src); wait1(v);
          while ((v.y != want) | (v.w != want)) {
            __builtin_amdgcn_s_sleep(2);
            ld16cc(v, src); wait1(v);
          }
          st16(mirx + (size_t)(r & RINGM) * 2048 + s * 64 + 2 * ln, v);
        }
      }

      // ---- readers: bounded mirror poll, sticky fallback to direct ------
      const u64* ma = mirx + (size_t)(r & RINGM) * 2048 + i2;        // h1
      const u64* mb = ma + 1024;                                     // h2
      const bool needB = (r >= 2);
      bool okA = false, okB = !needB;
      u32x4 va = {0, 0, 0, 0}, vb = {0, 0, 0, 0};
      if (!*(volatile int*)&useDir) {
        int it = 0;
        ld16l2(va, ma);
        if (needB) ld16l2(vb, mb);
        wait2(va, vb);
        for (;;) {
          okA = (va.y == wA) & (va.w == wA);
          if (needB) okB = (vb.y == wB) & (vb.w == wB);
          if ((okA & okB) | (++it > 2000)) break;
          __builtin_amdgcn_s_sleep(2);
          if (!okA) ld16l2(va, ma);
          if (needB && !okB) ld16l2(vb, mb);
          wait2(va, vb);
        }
        if (!(okA & okB)) *(volatile int*)&useDir = 1;  // benign race
      }
      if (!okA) {                                       // direct completion
        const u64* p = pub1 + (size_t)((r - 1) & RINGM) * HDIM + i2;
        va.x = (u32)pollslot(p, wA);
        va.z = (u32)pollslot(p + 1, wA);
      }
      if (!okB) {
        const u64* p = pub2 + (size_t)((r - 2) & RINGM) * HDIM + i2;
        vb.x = (u32)pollslot(p, wB);
        vb.z = (u32)pollslot(p + 1, wB);
      }
      hAr[i2]     = __uint_as_float(va.x);
      hAr[i2 + 1] = __uint_as_float(va.z);
      if (needB) {
        hBr[i2]     = __uint_as_float(vb.x);
        hBr[i2 + 1] = __uint_as_float(vb.z);
      }
    }
    __syncthreads();                         // staging complete for all waves

    const float4* hA4 = reinterpret_cast<const float4*>(hAr);
    const float4* hB4 = reinterpret_cast<const float4*>(hBr);

    // ---- compute phase --------------------------------------------------
    if (isL0) {
      if (r < TSTEPS) {
        float a0 = 0, a1 = 0, a2 = 0, a3 = 0;
        #pragma unroll
        for (int j = 0; j < 4; ++j) {
          float4 h4 = hA4[ln + (j << 6)];
          a0 += dot4(wrr[0][j], h4); a1 += dot4(wrr[1][j], h4);
          a2 += dot4(wrr[2][j], h4); a3 += dot4(wrr[3][j], h4);
        }
        #pragma unroll
        for (int d = 1; d < 64; d <<= 1) {
          a0 += __shfl_xor(a0, d); a1 += __shfl_xor(a1, d);
          a2 += __shfl_xor(a2, d); a3 += __shfl_xor(a3, d);
        }
        float g0 = a0 + bias[0], g1 = a1 + bias[1];
        float g2 = a2 + bias[2], g3 = a3 + bias[3];
        #pragma unroll
        for (int k = 0; k < 9; ++k) {
          g0 += wxr[0][k] * xr[k]; g1 += wxr[1][k] * xr[k];
          g2 += wxr[2][k] * xr[k]; g3 += wxr[3][k] * xr[k];
        }
        float gi = sigm(g0), gf = sigm(g1), gg = tanh_(g2), go = sigm(g3);
        c = gf * c + gi * gg;
        float h = go * tanh_(c);
        if (ln == 0)
          publish(pub1 + (size_t)(r & RINGM) * HDIM + unit, (u32)(r + 1), h);
      }
    } else {
      if (r >= 1) {                          // L1 step s = r-1
        float a0 = 0, a1 = 0, a2 = 0, a3 = 0;
        #pragma unroll
        for (int j = 0; j < 4; ++j) {
          float4 ha = hA4[ln + (j << 6)];
          float4 hb = hB4[ln + (j << 6)];
          a0 += dot4(wii[0][j], ha) + dot4(wrr[0][j], hb);
          a1 += dot4(wii[1][j], ha) + dot4(wrr[1][j], hb);
          a2 += dot4(wii[2][j], ha) + dot4(wrr[2][j], hb);
          a3 += dot4(wii[3][j], ha) + dot4(wrr[3][j], hb);
        }
        #pragma unroll
        for (int d = 1; d < 64; d <<= 1) {
          a0 += __shfl_xor(a0, d); a1 += __shfl_xor(a1, d);
          a2 += __shfl_xor(a2, d); a3 += __shfl_xor(a3, d);
        }
        float g0 = a0 + bias[0], g1 = a1 + bias[1];
        float g2 = a2 + bias[2], g3 = a3 + bias[3];
        float gi = sigm(g0), gf = sigm(g1), gg = tanh_(g2), go = sigm(g3);
        c = gf * c + gi * gg;
        float h = go * tanh_(c);
        if (ln == 0)
          publish(pub2 + (size_t)((r - 1) & RINGM) * HDIM + unit, (u32)r, h);
      }
    }
    // no trailing barrier: LDS staging is double-buffered by r&1
  }

  // ---- final Linear(h2[T-1]) by block 0 ----------------------------------
  if (b == 0) {
    const u64* s2 = pub2 + (size_t)((TSTEPS - 1) & RINGM) * HDIM;
    const int i2 = tid * 2;
    u64 va = pollslot(s2 + i2, (u32)TSTEPS);
    u64 vb = pollslot(s2 + i2 + 1, (u32)TSTEPS);
    float p = __uint_as_float((u32)va) * wlin[i2]
            + __uint_as_float((u32)vb) * wlin[i2 + 1];
    #pragma unroll
    for (int d = 1; d < 64; d <<= 1) p += __shfl_xor(p, d);
    if (ln == 0) red8[wv] = p;
    __syncthreads();
    if (tid == 0) {
      float s = blin[0];
      #pragma unroll
      for (int w = 0; w < 8; ++w) s += red8[w];
      out[0] = s;
    }
  }
}

extern "C" void kernel_launch(void* const* d_in, const int* in_sizes, int n_in,
                              void* d_out, int out_size, void* d_ws, size_t ws_size,
                              hipStream_t stream)
{
  const float* xin  = (const float*)d_in[0];
  const float* wih0 = (const float*)d_in[1];
  const float* whh0 = (const float*)d_in[2];
  const float* bih0 = (const float*)d_in[3];
  const float* bhh0 = (const float*)d_in[4];
  const float* wih1 = (const float*)d_in[5];
  const float* whh1 = (const float*)d_in[6];
  const float* bih1 = (const float*)d_in[7];
  const float* bhh1 = (const float*)d_in[8];
  const float* wlin = (const float*)d_in[9];
  const float* blin = (const float*)d_in[10];
  float* out = (float*)d_out;

  // ws layout: pub1 32KB | pub2 32KB | cnt (zeroed) | mir 512KB.
  char* ws = (char*)d_ws;
  u64* pub1 = (u64*)ws;                            // [4][1024]
  u64* pub2 = pub1 + 4 * HDIM;                     // [4][1024]
  u32* cnt  = (u32*)(ws + 64 * 1024);              // [8]
  u64* mir  = (u64*)(ws + 65 * 1024);              // [8][4][2048]

  hipMemsetAsync(cnt, 0, 8 * sizeof(u32), stream); // poison -> 0 (ranks)

  void* args[] = { &xin, &wih0, &whh0, &bih0, &bhh0,
                   &wih1, &whh1, &bih1, &bhh1, &wlin, &blin,
                   &out, &pub1, &pub2, &mir, &cnt };
  hipLaunchCooperativeKernel(reinterpret_cast<void*>(&lstm_fused),
                             dim3(NBLK), dim3(BS), args, 0, stream);
}